// Round 1
// baseline (1047.436 us; speedup 1.0000x reference)
//
#include <hip/hip_runtime.h>

// ---------------------------------------------------------------------------
// NSA attention forward for B=1, S=2048, HID=2048, H=16, D=128, L=32, NB=64,
// NSEL=8, WIN=512.  All inputs/outputs f32.  Internal MFMA compute in bf16
// (split hi/lo bf16 for the selection-critical Q/K projections).
// ---------------------------------------------------------------------------

#define SCALE_F 0.08838834764831845f   // 1/sqrt(128)

typedef short bf16x8 __attribute__((ext_vector_type(8)));
typedef short s16x4  __attribute__((ext_vector_type(4)));
typedef float f32x4  __attribute__((ext_vector_type(4)));

__device__ __forceinline__ short f2bf(float x) {
    unsigned u = __builtin_bit_cast(unsigned, x);
    u = (u + 0x7FFFu + ((u >> 16) & 1u)) >> 16;   // RNE
    return (short)(unsigned short)u;
}
__device__ __forceinline__ float bf2f(short b) {
    unsigned u = ((unsigned)(unsigned short)b) << 16;
    return __builtin_bit_cast(float, u);
}
__device__ __forceinline__ f32x4 mfma16(bf16x8 a, bf16x8 b, f32x4 c) {
    return __builtin_amdgcn_mfma_f32_16x16x32_bf16(a, b, c, 0, 0, 0);
}

// ---------------------------------------------------------------------------
// RoPE tables, mimicking the reference's f32 math: freq = 1/10000^(j/64)
// ---------------------------------------------------------------------------
__global__ __launch_bounds__(64) void rope_table_k(float* __restrict__ ct,
                                                   float* __restrict__ st) {
    int s = blockIdx.x, j = threadIdx.x;
    float fr  = 1.0f / powf(10000.0f, (float)j * (1.0f / 64.0f));
    float ang = (float)s * fr;
    ct[s * 64 + j] = cosf(ang);
    st[s * 64 + j] = sinf(ang);
}

// ---------------------------------------------------------------------------
// Projection GEMM: C(2048x2048) = X(2048x2048) @ W(2048x2048) + b,
// written as out[h][s][d] (head-major).  128x128 tile, BK=32, 4 waves (2x2),
// each wave 4x4 16x16x32 MFMAs.  SPLIT => hi/lo bf16 (3 MFMA per step) for
// near-f32 precision.  B staged transposed into LDS with an XOR k-swizzle.
// ---------------------------------------------------------------------------
template <bool SPLIT>
__global__ __launch_bounds__(256) void gemm_proj(
    const float* __restrict__ X,
    const float* __restrict__ W0, const float* __restrict__ b0, float* __restrict__ o0,
    const float* __restrict__ W1, const float* __restrict__ b1, float* __restrict__ o1)
{
    constexpr int P = SPLIT ? 2 : 1;
    const float* W    = (blockIdx.z == 0) ? W0 : W1;
    const float* bias = (blockIdx.z == 0) ? b0 : b1;
    float*       out  = (blockIdx.z == 0) ? o0 : o1;

    const int m0  = blockIdx.x * 128;
    const int h   = blockIdx.y;          // n0 = h*128 (one head per N-tile)
    const int tid = (int)threadIdx.x;
    const int l   = tid & 63, w = tid >> 6;
    const int wr  = w >> 1,  wc = w & 1;
    const int cc  = l & 15,  g  = l >> 4;

    __shared__ short As[P][128][40];     // [plane][m][k], +8 pad
    __shared__ short Bs[P][128][40];     // [plane][n][k swizzled], +8 pad

    f32x4 acc[4][4] = {};

    for (int k0 = 0; k0 < 2048; k0 += 32) {
        // ---- stage A tile (128 x 32) ----
        #pragma unroll
        for (int it = 0; it < 4; ++it) {
            int idx = tid + it * 256;            // 0..1023 float4s
            int row = idx >> 3;
            int c4  = (idx & 7) << 2;
            float4 x = *(const float4*)&X[(size_t)(m0 + row) * 2048 + k0 + c4];
            short h0 = f2bf(x.x), h1 = f2bf(x.y), h2 = f2bf(x.z), h3 = f2bf(x.w);
            s16x4 hv; hv[0] = h0; hv[1] = h1; hv[2] = h2; hv[3] = h3;
            *(s16x4*)&As[0][row][c4] = hv;
            if (SPLIT) {
                s16x4 lv;
                lv[0] = f2bf(x.x - bf2f(h0)); lv[1] = f2bf(x.y - bf2f(h1));
                lv[2] = f2bf(x.z - bf2f(h2)); lv[3] = f2bf(x.w - bf2f(h3));
                *(s16x4*)&As[P - 1][row][c4] = lv;
            }
        }
        // ---- stage B tile (32 x 128), transposed with XOR swizzle ----
        #pragma unroll
        for (int it = 0; it < 4; ++it) {
            int idx = tid + it * 256;            // 0..1023 float4s
            int kk  = idx >> 5;                  // 0..31
            int c4  = (idx & 31) << 2;           // 0..124
            float4 x = *(const float4*)&W[(size_t)(k0 + kk) * 2048 + h * 128 + c4];
            const float* xp = (const float*)&x;
            #pragma unroll
            for (int jj = 0; jj < 4; ++jj) {
                int n    = c4 + jj;
                int kcol = kk ^ (((n >> 2) & 3) << 3);
                short hi = f2bf(xp[jj]);
                Bs[0][n][kcol] = hi;
                if (SPLIT) Bs[P - 1][n][kcol] = f2bf(xp[jj] - bf2f(hi));
            }
        }
        __syncthreads();

        bf16x8 ah[4], bh[4];
        #pragma unroll
        for (int mt = 0; mt < 4; ++mt)
            ah[mt] = *(const bf16x8*)&As[0][wr * 64 + mt * 16 + cc][g * 8];
        #pragma unroll
        for (int nt = 0; nt < 4; ++nt) {
            int n = wc * 64 + nt * 16 + cc;
            bh[nt] = *(const bf16x8*)&Bs[0][n][(g * 8) ^ (((n >> 2) & 3) << 3)];
        }
        if (SPLIT) {
            bf16x8 al[4], bl[4];
            #pragma unroll
            for (int mt = 0; mt < 4; ++mt)
                al[mt] = *(const bf16x8*)&As[P - 1][wr * 64 + mt * 16 + cc][g * 8];
            #pragma unroll
            for (int nt = 0; nt < 4; ++nt) {
                int n = wc * 64 + nt * 16 + cc;
                bl[nt] = *(const bf16x8*)&Bs[P - 1][n][(g * 8) ^ (((n >> 2) & 3) << 3)];
            }
            #pragma unroll
            for (int mt = 0; mt < 4; ++mt)
                #pragma unroll
                for (int nt = 0; nt < 4; ++nt) {
                    acc[mt][nt] = mfma16(ah[mt], bh[nt], acc[mt][nt]);
                    acc[mt][nt] = mfma16(ah[mt], bl[nt], acc[mt][nt]);
                    acc[mt][nt] = mfma16(al[mt], bh[nt], acc[mt][nt]);
                }
        } else {
            #pragma unroll
            for (int mt = 0; mt < 4; ++mt)
                #pragma unroll
                for (int nt = 0; nt < 4; ++nt)
                    acc[mt][nt] = mfma16(ah[mt], bh[nt], acc[mt][nt]);
        }
        __syncthreads();
    }

    // epilogue: bias + write as out[h][s][d]
    #pragma unroll
    for (int mt = 0; mt < 4; ++mt)
        #pragma unroll
        for (int nt = 0; nt < 4; ++nt)
            #pragma unroll
            for (int j = 0; j < 4; ++j) {
                int srow = m0 + wr * 64 + mt * 16 + g * 4 + j;
                int col  = wc * 64 + nt * 16 + cc;
                out[((size_t)h * 2048 + srow) * 128 + col] =
                    acc[mt][nt][j] + bias[h * 128 + col];
            }
}

// ---------------------------------------------------------------------------
// In-place RoPE on qf and kf (layout [h][s][d]).
// ---------------------------------------------------------------------------
__global__ __launch_bounds__(256) void rope_apply(
    float* __restrict__ qf, float* __restrict__ kf,
    const float* __restrict__ ct, const float* __restrict__ st)
{
    int idx = blockIdx.x * 256 + (int)threadIdx.x;   // 2*16*2048*64
    int j = idx & 63;
    int s = (idx >> 6) & 2047;
    int h = (idx >> 17) & 15;
    int a = idx >> 21;
    float* p = (a ? kf : qf) + ((size_t)h * 2048 + s) * 128;
    float c = ct[s * 64 + j], sn = st[s * 64 + j];
    float x1 = p[j], x2 = p[j + 64];
    p[j]      = x1 * c - x2 * sn;
    p[j + 64] = x2 * c + x1 * sn;
}

// ---------------------------------------------------------------------------
// Block means of (roped) K and (raw) V: k_cmp/v_cmp [h][nb][d]
// ---------------------------------------------------------------------------
__global__ __launch_bounds__(256) void cmp_mean(
    const float* __restrict__ kf, const float* __restrict__ vf,
    float* __restrict__ kcmp, float* __restrict__ vcmp)
{
    int idx = blockIdx.x * 256 + (int)threadIdx.x;   // 16*64*128
    int d  = idx & 127;
    int nb = (idx >> 7) & 63;
    int h  = idx >> 13;
    const float* kp = &kf[((size_t)h * 2048 + nb * 32) * 128 + d];
    const float* vp = &vf[((size_t)h * 2048 + nb * 32) * 128 + d];
    float sk = 0.f, sv = 0.f;
    #pragma unroll
    for (int t = 0; t < 32; ++t) { sk += kp[t * 128]; sv += vp[t * 128]; }
    kcmp[((size_t)h * 64 + nb) * 128 + d] = sk * 0.03125f;
    vcmp[((size_t)h * 64 + nb) * 128 + d] = sv * 0.03125f;
}

// ---------------------------------------------------------------------------
// Compressed attention + top-8 block selection + gates.  One wave per (h,i).
// All f32 (selection precision).  Writes out_cmp, per-query block mask, gates.
// ---------------------------------------------------------------------------
__global__ __launch_bounds__(256) void cmp_attn(
    const float* __restrict__ qf, const float* __restrict__ kcmp,
    const float* __restrict__ vcmp,
    const float* __restrict__ Wg, const float* __restrict__ bg,
    float* __restrict__ ocmp, float* __restrict__ gout,
    unsigned long long* __restrict__ bmask)
{
    const int wid = blockIdx.x * 4 + ((int)threadIdx.x >> 6);
    const int l = (int)threadIdx.x & 63;
    const int h = wid >> 11;
    const int i = wid & 2047;

    const float* q  = &qf[((size_t)h * 2048 + i) * 128];
    const float* kc = &kcmp[((size_t)h * 64 + l) * 128];
    float dot = 0.f;
    #pragma unroll
    for (int d = 0; d < 128; d += 4) {
        float4 a = *(const float4*)&q[d];
        float4 b = *(const float4*)&kc[d];
        dot += a.x * b.x + a.y * b.y + a.z * b.z + a.w * b.w;
    }
    bool valid = ((l + 1) * 32 - 1) <= i;
    float s = valid ? dot * SCALE_F : -1e9f;     // NEG, matching reference
    float mx = s;
    #pragma unroll
    for (int off = 1; off < 64; off <<= 1) mx = fmaxf(mx, __shfl_xor(mx, off));
    float p = expf(s - mx);                      // all-masked row -> uniform
    float sum = p;
    #pragma unroll
    for (int off = 1; off < 64; off <<= 1) sum += __shfl_xor(sum, off);
    p /= sum;

    // top-8 by prob, ties -> lowest block index (jax.lax.top_k semantics)
    unsigned long long sel = 1ULL << (i >> 5);   // current block always in
    unsigned long long key = (1ULL << 45) |
        ((unsigned long long)__builtin_bit_cast(unsigned, p) << 7) |
        (unsigned long long)(63 - l);
    #pragma unroll
    for (int it = 0; it < 8; ++it) {
        unsigned long long k2 = key;
        #pragma unroll
        for (int off = 1; off < 64; off <<= 1) {
            unsigned long long o = __shfl_xor(k2, off);
            k2 = (o > k2) ? o : k2;
        }
        int wb = 63 - (int)(k2 & 63ULL);
        sel |= 1ULL << wb;
        if (l == wb) key = 0ULL;
    }
    if (l == 0) bmask[(size_t)h * 2048 + i] = sel;

    // out_cmp = p @ v_cmp   (zero when no complete block is causal)
    __shared__ float plds[4][64];
    const int wl = (int)threadIdx.x >> 6;
    plds[wl][l] = p;
    __syncthreads();
    bool hasblk = (i >= 31);
    #pragma unroll
    for (int r = 0; r < 2; ++r) {
        int d = l + r * 64;
        float acc = 0.f;
        if (hasblk) {
            for (int jb = 0; jb < 64; ++jb)
                acc += plds[wl][jb] * vcmp[((size_t)h * 64 + jb) * 128 + d];
        }
        ocmp[((size_t)h * 2048 + i) * 128 + d] = acc;
    }

    // gates: sigmoid(q . Wg[h,:,g] + bg)
    float pg0 = 0.f, pg1 = 0.f, pg2 = 0.f;
    #pragma unroll
    for (int r = 0; r < 2; ++r) {
        int d = l + r * 64;
        float qd = q[d];
        pg0 += qd * Wg[(size_t)(h * 128 + d) * 3 + 0];
        pg1 += qd * Wg[(size_t)(h * 128 + d) * 3 + 1];
        pg2 += qd * Wg[(size_t)(h * 128 + d) * 3 + 2];
    }
    #pragma unroll
    for (int off = 1; off < 64; off <<= 1) {
        pg0 += __shfl_xor(pg0, off);
        pg1 += __shfl_xor(pg1, off);
        pg2 += __shfl_xor(pg2, off);
    }
    if (l == 0) {
        gout[((size_t)h * 2048 + i) * 3 + 0] = 1.f / (1.f + expf(-(pg0 + bg[0])));
        gout[((size_t)h * 2048 + i) * 3 + 1] = 1.f / (1.f + expf(-(pg1 + bg[1])));
        gout[((size_t)h * 2048 + i) * 3 + 2] = 1.f / (1.f + expf(-(pg2 + bg[2])));
    }
}

// ---------------------------------------------------------------------------
// Main sparse attention: per (h, 64-query tile), iterate needed 64-token KV
// chunks (window + union of selected blocks).  MFMA QK^T and PV, dual online
// softmax (sel/win), then gated combine with out_cmp -> final output.
// ---------------------------------------------------------------------------
__global__ __launch_bounds__(256) void main_attn(
    const float* __restrict__ qf, const float* __restrict__ kf,
    const float* __restrict__ vf,
    const float* __restrict__ ocmp, const float* __restrict__ gates,
    const unsigned long long* __restrict__ bmask, float* __restrict__ out)
{
    const int h  = blockIdx.y;
    const int qt = blockIdx.x;
    const int i0 = qt * 64;
    const int tid = (int)threadIdx.x;
    const int l = tid & 63, w = tid >> 6;
    const int cc = l & 15,  g = l >> 4;

    __shared__ short Ks[64][136];        // K chunk   [tok][d], +8 pad
    __shared__ short Vt[128][72];        // V^T chunk [d][tok^swz], +8 pad
    __shared__ short Ps[2][4][16][72];   // P tiles   [branch][wave][row][tok]

    // union of selected-block masks over this tile's 64 queries
    unsigned long long um = bmask[(size_t)h * 2048 + i0 + l];
    #pragma unroll
    for (int off = 1; off < 64; off <<= 1) um |= __shfl_xor(um, off);

    unsigned long long bm[4];
    int mrow[4];
    #pragma unroll
    for (int j = 0; j < 4; ++j) {
        mrow[j] = i0 + w * 16 + g * 4 + j;             // C-layout rows
        bm[j] = bmask[(size_t)h * 2048 + mrow[j]];
    }

    // Q fragments (A layout: row = cc, k = kk*32 + g*8 + i)
    bf16x8 qfrag[4];
    {
        const float* qrow = &qf[((size_t)h * 2048 + i0 + w * 16 + cc) * 128];
        #pragma unroll
        for (int kk = 0; kk < 4; ++kk) {
            float4 xa = *(const float4*)&qrow[kk * 32 + g * 8];
            float4 xb = *(const float4*)&qrow[kk * 32 + g * 8 + 4];
            bf16x8 t;
            t[0] = f2bf(xa.x); t[1] = f2bf(xa.y); t[2] = f2bf(xa.z); t[3] = f2bf(xa.w);
            t[4] = f2bf(xb.x); t[5] = f2bf(xb.y); t[6] = f2bf(xb.z); t[7] = f2bf(xb.w);
            qfrag[kk] = t;
        }
    }

    f32x4 oacc[2][8] = {};
    float mrun[2][4], lrun[2][4];
    #pragma unroll
    for (int b = 0; b < 2; ++b)
        #pragma unroll
        for (int j = 0; j < 4; ++j) { mrun[b][j] = -1e30f; lrun[b][j] = 0.f; }

    for (int ch = 0; ch <= qt; ++ch) {
        bool needed = (ch >= qt - 8) || (((um >> (2 * ch)) & 3ULL) != 0ULL);
        if (!needed) continue;
        __syncthreads();   // previous PV reads complete before restage

        // ---- stage K chunk and swizzled V^T chunk (f32 -> bf16) ----
        #pragma unroll
        for (int it = 0; it < 8; ++it) {
            int idx = tid + it * 256;      // 0..2047 float4s
            int tok = idx >> 5;
            int d4  = (idx & 31) << 2;
            size_t base = ((size_t)h * 2048 + ch * 64 + tok) * 128 + d4;
            float4 kx = *(const float4*)&kf[base];
            s16x4 kv; kv[0] = f2bf(kx.x); kv[1] = f2bf(kx.y);
            kv[2] = f2bf(kx.z); kv[3] = f2bf(kx.w);
            *(s16x4*)&Ks[tok][d4] = kv;
            float4 vx = *(const float4*)&vf[base];
            const float* vp = (const float*)&vx;
            #pragma unroll
            for (int jj = 0; jj < 4; ++jj) {
                int d = d4 + jj;
                int colv = tok ^ (((d >> 2) & 7) << 3);
                Vt[d][colv] = f2bf(vp[jj]);
            }
        }
        __syncthreads();

        // ---- QK^T: 16 q-rows x 64 tokens per wave ----
        f32x4 sacc[4] = {};
        #pragma unroll
        for (int kk = 0; kk < 4; ++kk)
            #pragma unroll
            for (int nt = 0; nt < 4; ++nt) {
                bf16x8 kfr = *(const bf16x8*)&Ks[nt * 16 + cc][kk * 32 + g * 8];
                sacc[nt] = mfma16(qfrag[kk], kfr, sacc[nt]);
            }

        // ---- masks + dual online softmax, P -> LDS (bf16) ----
        #pragma unroll
        for (int b = 0; b < 2; ++b) {
            #pragma unroll
            for (int j = 0; j < 4; ++j) {
                const int iq = mrow[j];
                float sj[4]; bool ok[4];
                float mx = -1e30f;
                #pragma unroll
                for (int nt = 0; nt < 4; ++nt) {
                    int t = ch * 64 + nt * 16 + cc;
                    bool o = (t <= iq) &&
                             (b == 0 ? (((bm[j] >> (t >> 5)) & 1ULL) != 0ULL)
                                     : ((iq - t) < 512));
                    float s = sacc[nt][j] * SCALE_F;
                    sj[nt] = s; ok[nt] = o;
                    if (o) mx = fmaxf(mx, s);
                }
                #pragma unroll
                for (int off = 1; off < 16; off <<= 1)
                    mx = fmaxf(mx, __shfl_xor(mx, off));
                float mold = mrun[b][j];
                float mnew = fmaxf(mold, mx);
                float alpha = expf(mold - mnew);
                float psum = 0.f;
                #pragma unroll
                for (int nt = 0; nt < 4; ++nt) {
                    float p = ok[nt] ? expf(sj[nt] - mnew) : 0.f;
                    psum += p;
                    Ps[b][w][g * 4 + j][nt * 16 + cc] = f2bf(p);
                }
                #pragma unroll
                for (int off = 1; off < 16; off <<= 1)
                    psum += __shfl_xor(psum, off);
                mrun[b][j] = mnew;
                lrun[b][j] = lrun[b][j] * alpha + psum;
                #pragma unroll
                for (int nt2 = 0; nt2 < 8; ++nt2) oacc[b][nt2][j] *= alpha;
            }
        }
        __syncthreads();

        // ---- PV: O += P(16x64) @ V(64x128), both branches ----
        #pragma unroll
        for (int kk = 0; kk < 2; ++kk) {
            bf16x8 pa0 = *(const bf16x8*)&Ps[0][w][cc][kk * 32 + g * 8];
            bf16x8 pa1 = *(const bf16x8*)&Ps[1][w][cc][kk * 32 + g * 8];
            #pragma unroll
            for (int nt2 = 0; nt2 < 8; ++nt2) {
                int d = nt2 * 16 + cc;
                int colv = (kk * 32 + g * 8) ^ (((d >> 2) & 7) << 3);
                bf16x8 vfr = *(const bf16x8*)&Vt[d][colv];
                oacc[0][nt2] = mfma16(pa0, vfr, oacc[0][nt2]);
                oacc[1][nt2] = mfma16(pa1, vfr, oacc[1][nt2]);
            }
        }
    }

    // ---- epilogue: normalize, gate, combine with out_cmp ----
    #pragma unroll
    for (int j = 0; j < 4; ++j) {
        const int iq = mrow[j];
        float inv_s = 1.0f / lrun[0][j];
        float inv_w = 1.0f / lrun[1][j];
        float g0 = gates[((size_t)h * 2048 + iq) * 3 + 0];
        float g1 = gates[((size_t)h * 2048 + iq) * 3 + 1];
        float g2 = gates[((size_t)h * 2048 + iq) * 3 + 2];
        #pragma unroll
        for (int nt2 = 0; nt2 < 8; ++nt2) {
            int d = nt2 * 16 + cc;
            float cv = ocmp[((size_t)h * 2048 + iq) * 128 + d];
            float sv = oacc[0][nt2][j] * inv_s;
            float wv = oacc[1][nt2][j] * inv_w;
            out[(size_t)iq * 2048 + h * 128 + d] = g0 * cv + g1 * sv + g2 * wv;
        }
    }
}

// ---------------------------------------------------------------------------
// workspace layout (bytes)
// ---------------------------------------------------------------------------
#define OFF_QF   ((size_t)0)                      // 16 MB  q [h][s][d] f32
#define OFF_KF   ((size_t)16777216)               // 16 MB
#define OFF_VF   ((size_t)33554432)               // 16 MB
#define OFF_OCMP ((size_t)50331648)               // 16 MB
#define OFF_COS  ((size_t)67108864)               // 512 KB
#define OFF_SIN  ((size_t)67108864 + 524288)      // 512 KB
#define OFF_KC   ((size_t)67108864 + 1048576)     // 512 KB
#define OFF_VC   ((size_t)67108864 + 1572864)     // 512 KB
#define OFF_GATE ((size_t)67108864 + 2097152)     // 384 KB
#define OFF_BM   ((size_t)67108864 + 2490368)     // 256 KB  (end ~66.6 MB)

extern "C" void kernel_launch(void* const* d_in, const int* in_sizes, int n_in,
                              void* d_out, int out_size, void* d_ws, size_t ws_size,
                              hipStream_t stream)
{
    const float* X  = (const float*)d_in[0];
    const float* Wq = (const float*)d_in[1];
    const float* bq = (const float*)d_in[2];
    const float* Wk = (const float*)d_in[3];
    const float* bk = (const float*)d_in[4];
    const float* Wv = (const float*)d_in[5];
    const float* bv = (const float*)d_in[6];
    const float* Wg = (const float*)d_in[7];
    const float* bg = (const float*)d_in[8];
    float* out = (float*)d_out;

    char* ws = (char*)d_ws;
    float* qf    = (float*)(ws + OFF_QF);
    float* kfb   = (float*)(ws + OFF_KF);
    float* vfb   = (float*)(ws + OFF_VF);
    float* ocmp  = (float*)(ws + OFF_OCMP);
    float* cost  = (float*)(ws + OFF_COS);
    float* sint  = (float*)(ws + OFF_SIN);
    float* kcmp  = (float*)(ws + OFF_KC);
    float* vcmp  = (float*)(ws + OFF_VC);
    float* gatesb = (float*)(ws + OFF_GATE);
    unsigned long long* bmaskb = (unsigned long long*)(ws + OFF_BM);

    rope_table_k<<<2048, 64, 0, stream>>>(cost, sint);
    // Q and K projections in split (hi/lo) bf16 for selection-grade precision
    gemm_proj<true><<<dim3(16, 16, 2), 256, 0, stream>>>(X, Wq, bq, qf, Wk, bk, kfb);
    // V projection in plain bf16
    gemm_proj<false><<<dim3(16, 16, 1), 256, 0, stream>>>(X, Wv, bv, vfb, Wv, bv, vfb);
    rope_apply<<<16384, 256, 0, stream>>>(qf, kfb, cost, sint);
    cmp_mean<<<512, 256, 0, stream>>>(kfb, vfb, kcmp, vcmp);
    cmp_attn<<<8192, 256, 0, stream>>>(qf, kcmp, vcmp, Wg, bg, ocmp, gatesb, bmaskb);
    main_attn<<<dim3(32, 16), 256, 0, stream>>>(qf, kfb, vfb, ocmp, gatesb, bmaskb, out);
}

// Round 2
// 700.179 us; speedup vs baseline: 1.4960x; 1.4960x over previous
//
#include <hip/hip_runtime.h>

// ---------------------------------------------------------------------------
// NSA attention forward, B=1, S=2048, HID=2048, H=16, D=128, L=32, NB=64,
// NSEL=8, WIN=512.  f32 in/out.  bf16 MFMA compute (split hi/lo bf16 for the
// selection-critical Q/K projections).  Round 2: pre-converted bf16 planes,
// win/sel kernel split with direct-output accumulation, reg-staged prefetch.
// ---------------------------------------------------------------------------

#define SCALE_F 0.08838834764831845f                       // 1/sqrt(128)
#define SCL2E   (0.08838834764831845f * 1.4426950408889634f) // SCALE*log2(e)

typedef short  bf16x8 __attribute__((ext_vector_type(8)));
typedef short  s16x4  __attribute__((ext_vector_type(4)));
typedef float  f32x4  __attribute__((ext_vector_type(4)));

__device__ __forceinline__ unsigned short f2bfu(float x){
    unsigned u = __builtin_bit_cast(unsigned, x);
    u = (u + 0x7FFFu + ((u >> 16) & 1u)) >> 16;   // RNE
    return (unsigned short)u;
}
__device__ __forceinline__ float bf2f(unsigned short b){
    unsigned u = ((unsigned)b) << 16;
    return __builtin_bit_cast(float, u);
}
__device__ __forceinline__ f32x4 mfma16(bf16x8 a, bf16x8 b, f32x4 c){
    return __builtin_amdgcn_mfma_f32_16x16x32_bf16(a, b, c, 0, 0, 0);
}

// ---------------------------------------------------------------------------
// RoPE tables (f32 math mirroring reference)
// ---------------------------------------------------------------------------
__global__ __launch_bounds__(64) void rope_table_k(float* __restrict__ ct,
                                                   float* __restrict__ st){
    int s = blockIdx.x, j = threadIdx.x;
    float fr  = 1.0f / powf(10000.0f, (float)j * (1.0f / 64.0f));
    float ang = (float)s * fr;
    ct[s * 64 + j] = cosf(ang);
    st[s * 64 + j] = sinf(ang);
}

// ---------------------------------------------------------------------------
// Elementwise f32 -> bf16 (hi) and optional lo plane.  4 floats/thread.
// Grid: 4096 blocks x 256 (covers 2048*2048 floats).
// ---------------------------------------------------------------------------
template <bool LO>
__global__ __launch_bounds__(256) void prep_split(const float* __restrict__ src,
                                                  unsigned short* __restrict__ hi,
                                                  unsigned short* __restrict__ lo){
    size_t i = ((size_t)blockIdx.x * 256 + threadIdx.x) * 4;
    float4 x = *(const float4*)&src[i];
    unsigned short h0 = f2bfu(x.x), h1 = f2bfu(x.y), h2 = f2bfu(x.z), h3 = f2bfu(x.w);
    s16x4 hv; hv[0] = (short)h0; hv[1] = (short)h1; hv[2] = (short)h2; hv[3] = (short)h3;
    *(s16x4*)&hi[i] = hv;
    if (LO){
        s16x4 lv;
        lv[0] = (short)f2bfu(x.x - bf2f(h0)); lv[1] = (short)f2bfu(x.y - bf2f(h1));
        lv[2] = (short)f2bfu(x.z - bf2f(h2)); lv[3] = (short)f2bfu(x.w - bf2f(h3));
        *(s16x4*)&lo[i] = lv;
    }
}

// ---------------------------------------------------------------------------
// W (2048x2048, [k][n]) -> W^T bf16 planes ([n][k]), hi + optional lo.
// Grid: (32 k-tiles, 32 n-tiles), 64x64 tile per block.
// ---------------------------------------------------------------------------
__global__ __launch_bounds__(256) void prep_wT(const float* __restrict__ W,
                                               unsigned short* __restrict__ Th,
                                               unsigned short* __restrict__ Tl){
    __shared__ float T[64][65];
    const int k0 = blockIdx.x * 64, n0 = blockIdx.y * 64;
    const int tid = (int)threadIdx.x;
    #pragma unroll
    for (int it = 0; it < 16; ++it){
        int idx = tid + it * 256;
        int r = idx >> 6, c = idx & 63;
        T[c][r] = W[(size_t)(k0 + r) * 2048 + n0 + c];
    }
    __syncthreads();
    #pragma unroll
    for (int it = 0; it < 16; ++it){
        int idx = tid + it * 256;
        int n = idx >> 6, k = idx & 63;
        float v = T[n][k];
        unsigned short h = f2bfu(v);
        Th[(size_t)(n0 + n) * 2048 + k0 + k] = h;
        if (Tl) Tl[(size_t)(n0 + n) * 2048 + k0 + k] = f2bfu(v - bf2f(h));
    }
}

// ---------------------------------------------------------------------------
// GEMM from pre-converted bf16 planes.  C = A @ B^T_planes + bias.
// A planes: [2048][2048] bf16 (row-major, k fast).  B planes: W^T [n][k] bf16.
// 128x128 tile, BK=32, 4 waves, reg-prefetch double-buffering.
// P=2: split hi/lo (3 MFMA per pair).  Output: outF [h][s][128] f32, or
// outT [h][128][2048] bf16 transposed (for V).
// ---------------------------------------------------------------------------
template <int P>
__global__ __launch_bounds__(256) void gemm_bf(
    const unsigned short* __restrict__ Ah, const unsigned short* __restrict__ Al,
    const unsigned short* __restrict__ Bh, const unsigned short* __restrict__ Bl,
    const float* __restrict__ bias,
    float* __restrict__ outF, unsigned short* __restrict__ outT)
{
    const unsigned short* Ap[2] = {Ah, Al};
    const unsigned short* Bp[2] = {Bh, Bl};
    const int m0  = blockIdx.x * 128;
    const int h   = blockIdx.y;                 // n0 = h*128
    const int tid = (int)threadIdx.x;
    const int l   = tid & 63, w = tid >> 6;
    const int wr  = w >> 1,  wc = w & 1;
    const int cc  = l & 15,  g  = l >> 4;

    __shared__ short As[P][128][40];
    __shared__ short Bs[P][128][40];

    f32x4 acc[4][4] = {};
    bf16x8 ra[P][2], rb[P][2];

    auto LOADSTEP = [&](int k0){
        #pragma unroll
        for (int p = 0; p < P; ++p)
            #pragma unroll
            for (int it = 0; it < 2; ++it){
                int c = tid + it * 256;                  // 0..511
                int row = c >> 2, col8 = (c & 3) * 8;
                ra[p][it] = *(const bf16x8*)&Ap[p][(size_t)(m0 + row) * 2048 + k0 + col8];
                rb[p][it] = *(const bf16x8*)&Bp[p][(size_t)(h * 128 + row) * 2048 + k0 + col8];
            }
    };
    auto STORESTEP = [&](){
        #pragma unroll
        for (int p = 0; p < P; ++p)
            #pragma unroll
            for (int it = 0; it < 2; ++it){
                int c = tid + it * 256;
                int row = c >> 2, col8 = (c & 3) * 8;
                *(bf16x8*)&As[p][row][col8] = ra[p][it];
                *(bf16x8*)&Bs[p][row][col8] = rb[p][it];
            }
    };

    LOADSTEP(0); STORESTEP(); __syncthreads();
    for (int k0 = 0; k0 < 2048; k0 += 32){
        bool more = (k0 + 32) < 2048;
        if (more) LOADSTEP(k0 + 32);

        bf16x8 ah[4], bh[4];
        #pragma unroll
        for (int mt = 0; mt < 4; ++mt)
            ah[mt] = *(const bf16x8*)&As[0][wr * 64 + mt * 16 + cc][g * 8];
        #pragma unroll
        for (int nt = 0; nt < 4; ++nt)
            bh[nt] = *(const bf16x8*)&Bs[0][wc * 64 + nt * 16 + cc][g * 8];
        if (P == 2){
            bf16x8 al[4], bl[4];
            #pragma unroll
            for (int mt = 0; mt < 4; ++mt)
                al[mt] = *(const bf16x8*)&As[P - 1][wr * 64 + mt * 16 + cc][g * 8];
            #pragma unroll
            for (int nt = 0; nt < 4; ++nt)
                bl[nt] = *(const bf16x8*)&Bs[P - 1][wc * 64 + nt * 16 + cc][g * 8];
            #pragma unroll
            for (int mt = 0; mt < 4; ++mt)
                #pragma unroll
                for (int nt = 0; nt < 4; ++nt){
                    acc[mt][nt] = mfma16(ah[mt], bh[nt], acc[mt][nt]);
                    acc[mt][nt] = mfma16(ah[mt], bl[nt], acc[mt][nt]);
                    acc[mt][nt] = mfma16(al[mt], bh[nt], acc[mt][nt]);
                }
        } else {
            #pragma unroll
            for (int mt = 0; mt < 4; ++mt)
                #pragma unroll
                for (int nt = 0; nt < 4; ++nt)
                    acc[mt][nt] = mfma16(ah[mt], bh[nt], acc[mt][nt]);
        }
        __syncthreads();
        if (more){ STORESTEP(); __syncthreads(); }
    }

    #pragma unroll
    for (int mt = 0; mt < 4; ++mt)
        #pragma unroll
        for (int nt = 0; nt < 4; ++nt)
            #pragma unroll
            for (int j = 0; j < 4; ++j){
                int srow = m0 + wr * 64 + mt * 16 + g * 4 + j;
                int col  = wc * 64 + nt * 16 + cc;
                float v = acc[mt][nt][j] + bias[h * 128 + col];
                if (outF) outF[((size_t)h * 2048 + srow) * 128 + col] = v;
                else      outT[((size_t)h * 128 + col) * 2048 + srow] = f2bfu(v);
            }
}

// ---------------------------------------------------------------------------
// In-place RoPE on qf and kf (f32, [h][s][d]).
// ---------------------------------------------------------------------------
__global__ __launch_bounds__(256) void rope_apply(
    float* __restrict__ qf, float* __restrict__ kf,
    const float* __restrict__ ct, const float* __restrict__ st)
{
    int idx = blockIdx.x * 256 + (int)threadIdx.x;
    int j = idx & 63;
    int s = (idx >> 6) & 2047;
    int h = (idx >> 17) & 15;
    int a = idx >> 21;
    float* p = (a ? kf : qf) + ((size_t)h * 2048 + s) * 128;
    float c = ct[s * 64 + j], sn = st[s * 64 + j];
    float x1 = p[j], x2 = p[j + 64];
    p[j]      = x1 * c - x2 * sn;
    p[j + 64] = x2 * c + x1 * sn;
}

// ---------------------------------------------------------------------------
// Block means: k_cmp from roped f32 K; v_cmp from transposed bf16 V.
// ---------------------------------------------------------------------------
__global__ __launch_bounds__(256) void cmp_mean(
    const float* __restrict__ kf, const unsigned short* __restrict__ vtbf,
    float* __restrict__ kcmp, float* __restrict__ vcmp)
{
    int idx = blockIdx.x * 256 + (int)threadIdx.x;   // 16*64*128
    int d  = idx & 127;
    int nb = (idx >> 7) & 63;
    int h  = idx >> 13;
    const float* kp = &kf[((size_t)h * 2048 + nb * 32) * 128 + d];
    float sk = 0.f;
    #pragma unroll
    for (int t = 0; t < 32; ++t) sk += kp[t * 128];
    const unsigned short* vp = &vtbf[((size_t)h * 128 + d) * 2048 + nb * 32];
    float sv = 0.f;
    #pragma unroll
    for (int t = 0; t < 32; ++t) sv += bf2f(vp[t]);
    kcmp[((size_t)h * 64 + nb) * 128 + d] = sk * 0.03125f;
    vcmp[((size_t)h * 64 + nb) * 128 + d] = sv * 0.03125f;
}

// ---------------------------------------------------------------------------
// Compressed attention + top-8 selection + gates.  One wave per (h,i), f32.
// Writes g0*out_cmp directly into the output (base layer), plus gates+bmask.
// ---------------------------------------------------------------------------
__global__ __launch_bounds__(256) void cmp_attn(
    const float* __restrict__ qf, const float* __restrict__ kcmp,
    const float* __restrict__ vcmp,
    const float* __restrict__ Wg, const float* __restrict__ bg,
    float* __restrict__ out, float* __restrict__ gout,
    unsigned long long* __restrict__ bmask)
{
    const int wid = blockIdx.x * 4 + ((int)threadIdx.x >> 6);
    const int l = (int)threadIdx.x & 63;
    const int h = wid >> 11;
    const int i = wid & 2047;

    const float* q  = &qf[((size_t)h * 2048 + i) * 128];
    const float* kc = &kcmp[((size_t)h * 64 + l) * 128];
    float dot = 0.f;
    #pragma unroll
    for (int d = 0; d < 128; d += 4){
        float4 a = *(const float4*)&q[d];
        float4 b = *(const float4*)&kc[d];
        dot += a.x * b.x + a.y * b.y + a.z * b.z + a.w * b.w;
    }
    bool valid = ((l + 1) * 32 - 1) <= i;
    float s = valid ? dot * SCALE_F : -1e9f;
    float mx = s;
    #pragma unroll
    for (int off = 1; off < 64; off <<= 1) mx = fmaxf(mx, __shfl_xor(mx, off));
    float p = expf(s - mx);
    float sum = p;
    #pragma unroll
    for (int off = 1; off < 64; off <<= 1) sum += __shfl_xor(sum, off);
    p /= sum;

    // top-8 by prob; ties -> lowest block index (stable top_k)
    unsigned long long sel = 1ULL << (i >> 5);
    unsigned long long key = (1ULL << 45) |
        ((unsigned long long)__builtin_bit_cast(unsigned, p) << 7) |
        (unsigned long long)(63 - l);
    #pragma unroll
    for (int it = 0; it < 8; ++it){
        unsigned long long k2 = key;
        #pragma unroll
        for (int off = 1; off < 64; off <<= 1){
            unsigned long long o = __shfl_xor(k2, off);
            k2 = (o > k2) ? o : k2;
        }
        int wb = 63 - (int)(k2 & 63ULL);
        sel |= 1ULL << wb;
        if (l == wb) key = 0ULL;
    }
    if (l == 0) bmask[(size_t)h * 2048 + i] = sel;

    // gates (all lanes hold reduced sums)
    float pg0 = 0.f, pg1 = 0.f, pg2 = 0.f;
    #pragma unroll
    for (int r = 0; r < 2; ++r){
        int d = l + r * 64;
        float qd = q[d];
        pg0 += qd * Wg[(size_t)(h * 128 + d) * 3 + 0];
        pg1 += qd * Wg[(size_t)(h * 128 + d) * 3 + 1];
        pg2 += qd * Wg[(size_t)(h * 128 + d) * 3 + 2];
    }
    #pragma unroll
    for (int off = 1; off < 64; off <<= 1){
        pg0 += __shfl_xor(pg0, off);
        pg1 += __shfl_xor(pg1, off);
        pg2 += __shfl_xor(pg2, off);
    }
    float g0 = 1.f / (1.f + expf(-(pg0 + bg[0])));
    float g1 = 1.f / (1.f + expf(-(pg1 + bg[1])));
    float g2 = 1.f / (1.f + expf(-(pg2 + bg[2])));
    if (l == 0){
        gout[((size_t)h * 2048 + i) * 3 + 0] = g0;
        gout[((size_t)h * 2048 + i) * 3 + 1] = g1;
        gout[((size_t)h * 2048 + i) * 3 + 2] = g2;
    }

    // out = g0 * (p @ v_cmp)
    __shared__ float plds[4][64];
    const int wl = (int)threadIdx.x >> 6;
    plds[wl][l] = p;
    __syncthreads();
    bool hasblk = (i >= 31);
    #pragma unroll
    for (int r = 0; r < 2; ++r){
        int d = l + r * 64;
        float acc = 0.f;
        if (hasblk){
            for (int jb = 0; jb < 64; ++jb)
                acc += plds[wl][jb] * vcmp[((size_t)h * 64 + jb) * 128 + d];
        }
        out[(size_t)i * 2048 + h * 128 + d] = g0 * acc;
    }
}

// ---------------------------------------------------------------------------
// Single-branch sparse attention (IS_SEL: selected-blocks branch, heavy-first
// qt ordering; else: 512-window branch, exactly <=9 chunks).  64-query tile,
// 4 waves, reg-staged KV prefetch, exp2-domain online softmax.
// Accumulates g * O/l into out (on top of cmp_attn's base layer).
// ---------------------------------------------------------------------------
template <bool IS_SEL>
__global__ __launch_bounds__(256) void attn_main(
    const unsigned short* __restrict__ qbf,   // [h][s][128] bf16
    const unsigned short* __restrict__ kbf,   // [h][s][128] bf16
    const unsigned short* __restrict__ vtbf,  // [h][128][2048] bf16 (V^T)
    const float* __restrict__ gates,          // [h][s][3]
    const unsigned long long* __restrict__ bmask,
    float* __restrict__ out)                  // [s][2048], accumulate
{
    const int h  = blockIdx.y;
    const int qt = IS_SEL ? 31 - (int)blockIdx.x : (int)blockIdx.x;
    const int i0 = qt * 64;
    const int tid = (int)threadIdx.x;
    const int l = tid & 63, w = tid >> 6;
    const int cc = l & 15,  g = l >> 4;

    __shared__ short Ks[64][136];     // K chunk [tok][d], +8 pad
    __shared__ short Vt[128][72];     // V^T chunk [d][tok], +8 pad
    __shared__ short Ps[4][16][72];   // P [wave][row][tok], +8 pad

    unsigned long long um = 0;
    if (IS_SEL){
        um = bmask[(size_t)h * 2048 + i0 + l];
        #pragma unroll
        for (int off = 1; off < 64; off <<= 1) um |= __shfl_xor(um, off);
    }

    unsigned long long bm[4];
    int mrow[4];
    #pragma unroll
    for (int j = 0; j < 4; ++j){
        mrow[j] = i0 + w * 16 + g * 4 + j;
        bm[j] = IS_SEL ? bmask[(size_t)h * 2048 + mrow[j]] : 0ULL;
    }

    bf16x8 qfrag[4];
    {
        const unsigned short* qrow = &qbf[((size_t)h * 2048 + i0 + w * 16 + cc) * 128];
        #pragma unroll
        for (int kk = 0; kk < 4; ++kk)
            qfrag[kk] = *(const bf16x8*)&qrow[kk * 32 + g * 8];
    }

    f32x4 oacc[8] = {};
    float mrun[4], lrun[4];
    #pragma unroll
    for (int j = 0; j < 4; ++j){ mrun[j] = -1e30f; lrun[j] = 0.f; }

    const int chlo = IS_SEL ? 0 : (qt > 8 ? qt - 8 : 0);
    auto needed = [&](int ch)->bool {
        return IS_SEL ? (((um >> (2 * ch)) & 3ULL) != 0ULL) : true;
    };

    bf16x8 rk[4], rv[4];
    auto LOADC = [&](int ch){
        #pragma unroll
        for (int it = 0; it < 4; ++it){
            int c = tid + it * 256;   // 1024 16B-chunks each for K and V^T
            rk[it] = *(const bf16x8*)&kbf[((size_t)h * 2048 + ch * 64 + (c >> 4)) * 128 + (c & 15) * 8];
            rv[it] = *(const bf16x8*)&vtbf[((size_t)h * 128 + (c >> 3)) * 2048 + ch * 64 + (c & 7) * 8];
        }
    };
    auto STOREC = [&](){
        #pragma unroll
        for (int it = 0; it < 4; ++it){
            int c = tid + it * 256;
            *(bf16x8*)&Ks[c >> 4][(c & 15) * 8] = rk[it];
            *(bf16x8*)&Vt[c >> 3][(c & 7) * 8] = rv[it];
        }
    };

    int cur = chlo;
    while (cur <= qt && !needed(cur)) ++cur;   // chunk qt always needed
    LOADC(cur); STOREC(); __syncthreads();

    while (cur <= qt){
        int nxt = cur + 1;
        while (nxt <= qt && !needed(nxt)) ++nxt;
        const bool more = (nxt <= qt);
        if (more) LOADC(nxt);

        // ---- QK^T ----
        f32x4 sacc[4] = {};
        #pragma unroll
        for (int kk = 0; kk < 4; ++kk)
            #pragma unroll
            for (int nt = 0; nt < 4; ++nt){
                bf16x8 kfr = *(const bf16x8*)&Ks[nt * 16 + cc][kk * 32 + g * 8];
                sacc[nt] = mfma16(qfrag[kk], kfr, sacc[nt]);
            }

        // ---- masked online softmax (exp2 domain) ----
        const int tbase = cur * 64;
        #pragma unroll
        for (int j = 0; j < 4; ++j){
            const int iq = mrow[j];
            float sj[4]; bool ok[4];
            float mx = -1e30f;
            #pragma unroll
            for (int nt = 0; nt < 4; ++nt){
                int t = tbase + nt * 16 + cc;
                bool o = (t <= iq) &&
                         (IS_SEL ? (((bm[j] >> (t >> 5)) & 1ULL) != 0ULL)
                                 : ((iq - t) < 512));
                float s = sacc[nt][j] * SCL2E;
                sj[nt] = s; ok[nt] = o;
                if (o) mx = fmaxf(mx, s);
            }
            #pragma unroll
            for (int off = 1; off < 16; off <<= 1)
                mx = fmaxf(mx, __shfl_xor(mx, off));
            float mnew = fmaxf(mrun[j], mx);
            float alpha = exp2f(mrun[j] - mnew);
            float psum = 0.f;
            #pragma unroll
            for (int nt = 0; nt < 4; ++nt){
                float p = ok[nt] ? exp2f(sj[nt] - mnew) : 0.f;
                psum += p;
                Ps[w][g * 4 + j][nt * 16 + cc] = (short)f2bfu(p);
            }
            #pragma unroll
            for (int off = 1; off < 16; off <<= 1)
                psum += __shfl_xor(psum, off);
            mrun[j] = mnew;
            lrun[j] = lrun[j] * alpha + psum;
            #pragma unroll
            for (int nt2 = 0; nt2 < 8; ++nt2) oacc[nt2][j] *= alpha;
        }
        __syncthreads();

        // ---- PV ----
        #pragma unroll
        for (int kk = 0; kk < 2; ++kk){
            bf16x8 pa = *(const bf16x8*)&Ps[w][cc][kk * 32 + g * 8];
            #pragma unroll
            for (int nt2 = 0; nt2 < 8; ++nt2){
                bf16x8 vfr = *(const bf16x8*)&Vt[nt2 * 16 + cc][kk * 32 + g * 8];
                oacc[nt2] = mfma16(pa, vfr, oacc[nt2]);
            }
        }
        __syncthreads();
        if (more){ STOREC(); __syncthreads(); }
        cur = more ? nxt : qt + 1;
    }

    // ---- epilogue: out += g * O / l ----
    const int GI = IS_SEL ? 1 : 2;
    #pragma unroll
    for (int j = 0; j < 4; ++j){
        const int iq = mrow[j];
        float gv  = gates[((size_t)h * 2048 + iq) * 3 + GI];
        float inv = gv / lrun[j];      // lrun > 0 (diagonal token always live)
        #pragma unroll
        for (int nt2 = 0; nt2 < 8; ++nt2){
            int d = nt2 * 16 + cc;
            out[(size_t)iq * 2048 + h * 128 + d] += oacc[nt2][j] * inv;
        }
    }
}

// ---------------------------------------------------------------------------
// workspace layout (bytes); peak ~74.7 MB
// ---------------------------------------------------------------------------
#define MB ((size_t)1 << 20)
#define OFF_QF   ((size_t)0)          // 16 MB  q f32 [h][s][d]
#define OFF_KF   (16 * MB)            // 16 MB  k f32
#define OFF_VT   (32 * MB)            //  8 MB  V^T bf16 [h][d][s]
#define OFF_XH   (40 * MB)            //  8 MB  X hi bf16   (later: qbf)
#define OFF_XL   (48 * MB)            //  8 MB  X lo bf16   (later: kbf)
#define OFF_WTH  (56 * MB)            //  8 MB  W^T hi bf16 (per-matrix reuse)
#define OFF_WTL  (64 * MB)            //  8 MB  W^T lo bf16
#define OFF_COS  (72 * MB)
#define OFF_SIN  (72 * MB + 524288)
#define OFF_KC   (72 * MB + 1048576)
#define OFF_VC   (72 * MB + 1572864)
#define OFF_GATE (72 * MB + 2097152)
#define OFF_BM   (72 * MB + 2490368)

extern "C" void kernel_launch(void* const* d_in, const int* in_sizes, int n_in,
                              void* d_out, int out_size, void* d_ws, size_t ws_size,
                              hipStream_t stream)
{
    const float* X  = (const float*)d_in[0];
    const float* Wq = (const float*)d_in[1];
    const float* bq = (const float*)d_in[2];
    const float* Wk = (const float*)d_in[3];
    const float* bk = (const float*)d_in[4];
    const float* Wv = (const float*)d_in[5];
    const float* bv = (const float*)d_in[6];
    const float* Wg = (const float*)d_in[7];
    const float* bg = (const float*)d_in[8];
    float* out = (float*)d_out;

    char* ws = (char*)d_ws;
    float* qf   = (float*)(ws + OFF_QF);
    float* kf   = (float*)(ws + OFF_KF);
    unsigned short* vtbf = (unsigned short*)(ws + OFF_VT);
    unsigned short* Xh   = (unsigned short*)(ws + OFF_XH);
    unsigned short* Xl   = (unsigned short*)(ws + OFF_XL);
    unsigned short* WTh  = (unsigned short*)(ws + OFF_WTH);
    unsigned short* WTl  = (unsigned short*)(ws + OFF_WTL);
    unsigned short* qbf  = (unsigned short*)(ws + OFF_XH);   // alias (X dead)
    unsigned short* kbf  = (unsigned short*)(ws + OFF_XL);   // alias
    float* cost  = (float*)(ws + OFF_COS);
    float* sint  = (float*)(ws + OFF_SIN);
    float* kcmp  = (float*)(ws + OFF_KC);
    float* vcmp  = (float*)(ws + OFF_VC);
    float* gatesb = (float*)(ws + OFF_GATE);
    unsigned long long* bmaskb = (unsigned long long*)(ws + OFF_BM);

    rope_table_k<<<2048, 64, 0, stream>>>(cost, sint);
    prep_split<true><<<4096, 256, 0, stream>>>(X, Xh, Xl);

    prep_wT<<<dim3(32, 32), 256, 0, stream>>>(Wq, WTh, WTl);
    gemm_bf<2><<<dim3(16, 16), 256, 0, stream>>>(Xh, Xl, WTh, WTl, bq, qf, nullptr);
    prep_wT<<<dim3(32, 32), 256, 0, stream>>>(Wk, WTh, WTl);
    gemm_bf<2><<<dim3(16, 16), 256, 0, stream>>>(Xh, Xl, WTh, WTl, bk, kf, nullptr);
    prep_wT<<<dim3(32, 32), 256, 0, stream>>>(Wv, WTh, nullptr);
    gemm_bf<1><<<dim3(16, 16), 256, 0, stream>>>(Xh, nullptr, WTh, nullptr, bv, nullptr, vtbf);

    rope_apply<<<16384, 256, 0, stream>>>(qf, kf, cost, sint);
    prep_split<false><<<4096, 256, 0, stream>>>(qf, qbf, nullptr);
    prep_split<false><<<4096, 256, 0, stream>>>(kf, kbf, nullptr);

    cmp_mean<<<512, 256, 0, stream>>>(kf, vtbf, kcmp, vcmp);
    cmp_attn<<<8192, 256, 0, stream>>>(qf, kcmp, vcmp, Wg, bg, out, gatesb, bmaskb);

    attn_main<false><<<dim3(32, 16), 256, 0, stream>>>(qbf, kbf, vtbf, gatesb, bmaskb, out);
    attn_main<true><<<dim3(32, 16), 256, 0, stream>>>(qbf, kbf, vtbf, gatesb, bmaskb, out);
}

// Round 3
// 597.722 us; speedup vs baseline: 1.7524x; 1.1714x over previous
//
#include <hip/hip_runtime.h>

// ---------------------------------------------------------------------------
// NSA attention forward, B=1, S=2048, HID=2048, H=16, D=128, L=32, NB=64,
// NSEL=8, WIN=512.  f32 in/out.  bf16 MFMA compute (split hi/lo bf16 for the
// selection-critical Q/K projections; f32 VALU for selection-critical cmp
// scores).  Round 3: tiled cmp_attn (LDS f32 score GEMM + MFMA PV) + gates_k.
// ---------------------------------------------------------------------------

#define SCALE_F 0.08838834764831845f                       // 1/sqrt(128)
#define SCL2E   (0.08838834764831845f * 1.4426950408889634f) // SCALE*log2(e)

typedef short  bf16x8 __attribute__((ext_vector_type(8)));
typedef short  s16x4  __attribute__((ext_vector_type(4)));
typedef float  f32x4  __attribute__((ext_vector_type(4)));

__device__ __forceinline__ unsigned short f2bfu(float x){
    unsigned u = __builtin_bit_cast(unsigned, x);
    u = (u + 0x7FFFu + ((u >> 16) & 1u)) >> 16;   // RNE
    return (unsigned short)u;
}
__device__ __forceinline__ float bf2f(unsigned short b){
    unsigned u = ((unsigned)b) << 16;
    return __builtin_bit_cast(float, u);
}
__device__ __forceinline__ f32x4 mfma16(bf16x8 a, bf16x8 b, f32x4 c){
    return __builtin_amdgcn_mfma_f32_16x16x32_bf16(a, b, c, 0, 0, 0);
}

// ---------------------------------------------------------------------------
// RoPE tables (f32 math mirroring reference)
// ---------------------------------------------------------------------------
__global__ __launch_bounds__(64) void rope_table_k(float* __restrict__ ct,
                                                   float* __restrict__ st){
    int s = blockIdx.x, j = threadIdx.x;
    float fr  = 1.0f / powf(10000.0f, (float)j * (1.0f / 64.0f));
    float ang = (float)s * fr;
    ct[s * 64 + j] = cosf(ang);
    st[s * 64 + j] = sinf(ang);
}

// ---------------------------------------------------------------------------
// Elementwise f32 -> bf16 (hi) and optional lo plane.  4 floats/thread.
// ---------------------------------------------------------------------------
template <bool LO>
__global__ __launch_bounds__(256) void prep_split(const float* __restrict__ src,
                                                  unsigned short* __restrict__ hi,
                                                  unsigned short* __restrict__ lo){
    size_t i = ((size_t)blockIdx.x * 256 + threadIdx.x) * 4;
    float4 x = *(const float4*)&src[i];
    unsigned short h0 = f2bfu(x.x), h1 = f2bfu(x.y), h2 = f2bfu(x.z), h3 = f2bfu(x.w);
    s16x4 hv; hv[0] = (short)h0; hv[1] = (short)h1; hv[2] = (short)h2; hv[3] = (short)h3;
    *(s16x4*)&hi[i] = hv;
    if (LO){
        s16x4 lv;
        lv[0] = (short)f2bfu(x.x - bf2f(h0)); lv[1] = (short)f2bfu(x.y - bf2f(h1));
        lv[2] = (short)f2bfu(x.z - bf2f(h2)); lv[3] = (short)f2bfu(x.w - bf2f(h3));
        *(s16x4*)&lo[i] = lv;
    }
}

// ---------------------------------------------------------------------------
// W (2048x2048, [k][n]) -> W^T bf16 planes ([n][k]), hi + optional lo.
// ---------------------------------------------------------------------------
__global__ __launch_bounds__(256) void prep_wT(const float* __restrict__ W,
                                               unsigned short* __restrict__ Th,
                                               unsigned short* __restrict__ Tl){
    __shared__ float T[64][65];
    const int k0 = blockIdx.x * 64, n0 = blockIdx.y * 64;
    const int tid = (int)threadIdx.x;
    #pragma unroll
    for (int it = 0; it < 16; ++it){
        int idx = tid + it * 256;
        int r = idx >> 6, c = idx & 63;
        T[c][r] = W[(size_t)(k0 + r) * 2048 + n0 + c];
    }
    __syncthreads();
    #pragma unroll
    for (int it = 0; it < 16; ++it){
        int idx = tid + it * 256;
        int n = idx >> 6, k = idx & 63;
        float v = T[n][k];
        unsigned short h = f2bfu(v);
        Th[(size_t)(n0 + n) * 2048 + k0 + k] = h;
        if (Tl) Tl[(size_t)(n0 + n) * 2048 + k0 + k] = f2bfu(v - bf2f(h));
    }
}

// ---------------------------------------------------------------------------
// GEMM from pre-converted bf16 planes.  C = A @ B^T_planes + bias.
// 128x128 tile, BK=32, 4 waves, reg-prefetch double-buffering.
// ---------------------------------------------------------------------------
template <int P>
__global__ __launch_bounds__(256) void gemm_bf(
    const unsigned short* __restrict__ Ah, const unsigned short* __restrict__ Al,
    const unsigned short* __restrict__ Bh, const unsigned short* __restrict__ Bl,
    const float* __restrict__ bias,
    float* __restrict__ outF, unsigned short* __restrict__ outT)
{
    const unsigned short* Ap[2] = {Ah, Al};
    const unsigned short* Bp[2] = {Bh, Bl};
    const int m0  = blockIdx.x * 128;
    const int h   = blockIdx.y;                 // n0 = h*128
    const int tid = (int)threadIdx.x;
    const int l   = tid & 63, w = tid >> 6;
    const int wr  = w >> 1,  wc = w & 1;
    const int cc  = l & 15,  g  = l >> 4;

    __shared__ short As[P][128][40];
    __shared__ short Bs[P][128][40];

    f32x4 acc[4][4] = {};
    bf16x8 ra[P][2], rb[P][2];

    auto LOADSTEP = [&](int k0){
        #pragma unroll
        for (int p = 0; p < P; ++p)
            #pragma unroll
            for (int it = 0; it < 2; ++it){
                int c = tid + it * 256;                  // 0..511
                int row = c >> 2, col8 = (c & 3) * 8;
                ra[p][it] = *(const bf16x8*)&Ap[p][(size_t)(m0 + row) * 2048 + k0 + col8];
                rb[p][it] = *(const bf16x8*)&Bp[p][(size_t)(h * 128 + row) * 2048 + k0 + col8];
            }
    };
    auto STORESTEP = [&](){
        #pragma unroll
        for (int p = 0; p < P; ++p)
            #pragma unroll
            for (int it = 0; it < 2; ++it){
                int c = tid + it * 256;
                int row = c >> 2, col8 = (c & 3) * 8;
                *(bf16x8*)&As[p][row][col8] = ra[p][it];
                *(bf16x8*)&Bs[p][row][col8] = rb[p][it];
            }
    };

    LOADSTEP(0); STORESTEP(); __syncthreads();
    for (int k0 = 0; k0 < 2048; k0 += 32){
        bool more = (k0 + 32) < 2048;
        if (more) LOADSTEP(k0 + 32);

        bf16x8 ah[4], bh[4];
        #pragma unroll
        for (int mt = 0; mt < 4; ++mt)
            ah[mt] = *(const bf16x8*)&As[0][wr * 64 + mt * 16 + cc][g * 8];
        #pragma unroll
        for (int nt = 0; nt < 4; ++nt)
            bh[nt] = *(const bf16x8*)&Bs[0][wc * 64 + nt * 16 + cc][g * 8];
        if (P == 2){
            bf16x8 al[4], bl[4];
            #pragma unroll
            for (int mt = 0; mt < 4; ++mt)
                al[mt] = *(const bf16x8*)&As[P - 1][wr * 64 + mt * 16 + cc][g * 8];
            #pragma unroll
            for (int nt = 0; nt < 4; ++nt)
                bl[nt] = *(const bf16x8*)&Bs[P - 1][wc * 64 + nt * 16 + cc][g * 8];
            #pragma unroll
            for (int mt = 0; mt < 4; ++mt)
                #pragma unroll
                for (int nt = 0; nt < 4; ++nt){
                    acc[mt][nt] = mfma16(ah[mt], bh[nt], acc[mt][nt]);
                    acc[mt][nt] = mfma16(ah[mt], bl[nt], acc[mt][nt]);
                    acc[mt][nt] = mfma16(al[mt], bh[nt], acc[mt][nt]);
                }
        } else {
            #pragma unroll
            for (int mt = 0; mt < 4; ++mt)
                #pragma unroll
                for (int nt = 0; nt < 4; ++nt)
                    acc[mt][nt] = mfma16(ah[mt], bh[nt], acc[mt][nt]);
        }
        __syncthreads();
        if (more){ STORESTEP(); __syncthreads(); }
    }

    #pragma unroll
    for (int mt = 0; mt < 4; ++mt)
        #pragma unroll
        for (int nt = 0; nt < 4; ++nt)
            #pragma unroll
            for (int j = 0; j < 4; ++j){
                int srow = m0 + wr * 64 + mt * 16 + g * 4 + j;
                int col  = wc * 64 + nt * 16 + cc;
                float v = acc[mt][nt][j] + bias[h * 128 + col];
                if (outF) outF[((size_t)h * 2048 + srow) * 128 + col] = v;
                else      outT[((size_t)h * 128 + col) * 2048 + srow] = f2bfu(v);
            }
}

// ---------------------------------------------------------------------------
// In-place RoPE on qf and kf (f32, [h][s][d]).
// ---------------------------------------------------------------------------
__global__ __launch_bounds__(256) void rope_apply(
    float* __restrict__ qf, float* __restrict__ kf,
    const float* __restrict__ ct, const float* __restrict__ st)
{
    int idx = blockIdx.x * 256 + (int)threadIdx.x;
    int j = idx & 63;
    int s = (idx >> 6) & 2047;
    int h = (idx >> 17) & 15;
    int a = idx >> 21;
    float* p = (a ? kf : qf) + ((size_t)h * 2048 + s) * 128;
    float c = ct[s * 64 + j], sn = st[s * 64 + j];
    float x1 = p[j], x2 = p[j + 64];
    p[j]      = x1 * c - x2 * sn;
    p[j + 64] = x2 * c + x1 * sn;
}

// ---------------------------------------------------------------------------
// Block means: k_cmp from roped f32 K; v_cmp from transposed bf16 V.
// ---------------------------------------------------------------------------
__global__ __launch_bounds__(256) void cmp_mean(
    const float* __restrict__ kf, const unsigned short* __restrict__ vtbf,
    float* __restrict__ kcmp, float* __restrict__ vcmp)
{
    int idx = blockIdx.x * 256 + (int)threadIdx.x;   // 16*64*128
    int d  = idx & 127;
    int nb = (idx >> 7) & 63;
    int h  = idx >> 13;
    const float* kp = &kf[((size_t)h * 2048 + nb * 32) * 128 + d];
    float sk = 0.f;
    #pragma unroll
    for (int t = 0; t < 32; ++t) sk += kp[t * 128];
    const unsigned short* vp = &vtbf[((size_t)h * 128 + d) * 2048 + nb * 32];
    float sv = 0.f;
    #pragma unroll
    for (int t = 0; t < 32; ++t) sv += bf2f(vp[t]);
    kcmp[((size_t)h * 64 + nb) * 128 + d] = sk * 0.03125f;
    vcmp[((size_t)h * 64 + nb) * 128 + d] = sv * 0.03125f;
}

// ---------------------------------------------------------------------------
// Gates: g = sigmoid(q . Wg[h,:,gi] + bg[gi]).  One thread per (h,i,gi).
// ---------------------------------------------------------------------------
__global__ __launch_bounds__(256) void gates_k(
    const float* __restrict__ qf, const float* __restrict__ Wg,
    const float* __restrict__ bg, float* __restrict__ gout)
{
    int Gn = blockIdx.x * 256 + (int)threadIdx.x;
    int sub = Gn & 3, qh = Gn >> 2;        // qh: (h*2048 + i), 0..32767
    if (sub == 3) return;
    int h = qh >> 11;
    const float* q  = &qf[(size_t)qh * 128];
    const float* wg = &Wg[(size_t)h * 384 + sub];
    float acc = 0.f;
    #pragma unroll 4
    for (int k = 0; k < 128; ++k) acc += q[k] * wg[k * 3];
    gout[(size_t)qh * 3 + sub] = 1.f / (1.f + expf(-(acc + bg[sub])));
}

// ---------------------------------------------------------------------------
// Compressed attention + top-8 selection, tiled: one block per (qtile, head).
// Phase A: f32 64x64x128 score GEMM from LDS (XOR-swizzled float4 chunks,
// 4x4 register blocking) -- full f32 precision for selection.
// Phase B: per-wave softmax + shuffle top-k; PV via bf16 MFMA.
// Writes out = g0 * out_cmp (base layer) + bmask.
// ---------------------------------------------------------------------------
__global__ __launch_bounds__(256) void cmp_attn(
    const float* __restrict__ qf, const float* __restrict__ kcmp,
    const float* __restrict__ vcmp, const float* __restrict__ gout,
    float* __restrict__ out, unsigned long long* __restrict__ bmask)
{
    const int h = blockIdx.y, qt = blockIdx.x, i0 = qt * 64;
    const int tid = (int)threadIdx.x;
    const int l = tid & 63, w = tid >> 6;
    const int ty = tid >> 4, tx = tid & 15;
    const int cc = l & 15, g = l >> 4;

    __shared__ __align__(16) char smem[65536];
    float4* qs4 = (float4*)smem;                                  // [64][32]
    float4* kc4 = (float4*)(smem + 32768);                        // [64][32]
    // phase-B aliases:
    unsigned short* vcT = (unsigned short*)smem;                  // [128][72]
    float* sc = (float*)(smem + 32768);                           // [64][68]
    unsigned short* ps = (unsigned short*)(smem + 32768 + 17408); // [64][72]

    // ---- stage Q tile and k_cmp (f32, XOR-swizzled float4 chunks) ----
    #pragma unroll
    for (int it = 0; it < 8; ++it){
        int idx = tid + it * 256;            // 0..2047
        int row = idx >> 5, c = idx & 31;
        int cs = c ^ ((row >> 2) & 7);
        qs4[row * 32 + cs] = *(const float4*)&qf[((size_t)h * 2048 + i0 + row) * 128 + c * 4];
        kc4[row * 32 + cs] = *(const float4*)&kcmp[((size_t)h * 64 + row) * 128 + c * 4];
    }
    __syncthreads();

    // ---- scores: 64x64x128 f32, 4 rows x 4 cols per thread ----
    float acc[4][4] = {};
    #pragma unroll 2
    for (int k0 = 0; k0 < 32; ++k0){
        float4 qv[4], kv[4];
        #pragma unroll
        for (int j = 0; j < 4; ++j) qv[j] = qs4[(4 * ty + j) * 32 + (k0 ^ (ty & 7))];
        #pragma unroll
        for (int c = 0; c < 4; ++c) kv[c] = kc4[(4 * tx + c) * 32 + (k0 ^ (tx & 7))];
        #pragma unroll
        for (int j = 0; j < 4; ++j)
            #pragma unroll
            for (int c = 0; c < 4; ++c)
                acc[j][c] += qv[j].x * kv[c].x + qv[j].y * kv[c].y
                           + qv[j].z * kv[c].z + qv[j].w * kv[c].w;
    }
    __syncthreads();   // all qs4/kc4 reads done; safe to overwrite regions

    // ---- write masked scores to sc; stage V^T bf16 into vcT ----
    #pragma unroll
    for (int j = 0; j < 4; ++j){
        int r = 4 * ty + j, i = i0 + r;
        float4 sv;
        float* svp = (float*)&sv;
        #pragma unroll
        for (int c = 0; c < 4; ++c){
            int b = 4 * tx + c;
            svp[c] = (b * 32 + 31 <= i) ? acc[j][c] * SCALE_F : -1e9f;
        }
        *(float4*)&sc[r * 68 + 4 * tx] = sv;
    }
    #pragma unroll
    for (int it = 0; it < 8; ++it){
        int idx = tid + it * 256;            // 0..2047
        int jb = idx >> 5, d4 = (idx & 31) * 4;
        float4 vx = *(const float4*)&vcmp[((size_t)h * 64 + jb) * 128 + d4];
        const float* vp = (const float*)&vx;
        #pragma unroll
        for (int jj = 0; jj < 4; ++jj)
            vcT[(d4 + jj) * 72 + jb] = f2bfu(vp[jj]);
    }
    __syncthreads();

    // ---- per-wave softmax + top-8 (16 queries per wave) ----
    for (int qq = 0; qq < 16; ++qq){
        const int q = w * 16 + qq;
        float s = sc[q * 68 + l];
        float mx = s;
        #pragma unroll
        for (int off = 1; off < 64; off <<= 1) mx = fmaxf(mx, __shfl_xor(mx, off));
        float p = expf(s - mx);
        float sum = p;
        #pragma unroll
        for (int off = 1; off < 64; off <<= 1) sum += __shfl_xor(sum, off);
        p /= sum;
        ps[q * 72 + l] = f2bfu(p);

        unsigned long long sel = 1ULL << ((i0 + q) >> 5);
        unsigned long long key = (1ULL << 45) |
            ((unsigned long long)__builtin_bit_cast(unsigned, p) << 7) |
            (unsigned long long)(63 - l);
        #pragma unroll
        for (int it = 0; it < 8; ++it){
            unsigned long long k2 = key;
            #pragma unroll
            for (int off = 1; off < 64; off <<= 1){
                unsigned long long o = __shfl_xor(k2, off);
                k2 = (o > k2) ? o : k2;
            }
            int wb = 63 - (int)(k2 & 63ULL);
            sel |= 1ULL << wb;
            if (l == wb) key = 0ULL;
        }
        if (l == 0) bmask[(size_t)h * 2048 + i0 + q] = sel;
    }
    __syncthreads();

    // ---- PV: out_cmp(16x128 per wave) = P @ v_cmp via bf16 MFMA ----
    f32x4 oacc[8] = {};
    #pragma unroll
    for (int kk = 0; kk < 2; ++kk){
        bf16x8 pa = *(const bf16x8*)&ps[(w * 16 + cc) * 72 + kk * 32 + g * 8];
        #pragma unroll
        for (int nt2 = 0; nt2 < 8; ++nt2){
            bf16x8 vfr = *(const bf16x8*)&vcT[(nt2 * 16 + cc) * 72 + kk * 32 + g * 8];
            oacc[nt2] = mfma16(pa, vfr, oacc[nt2]);
        }
    }
    #pragma unroll
    for (int j = 0; j < 4; ++j){
        int q = w * 16 + g * 4 + j, iq = i0 + q;
        float g0 = gout[((size_t)h * 2048 + iq) * 3];
        float f = (iq >= 31) ? g0 : 0.f;
        #pragma unroll
        for (int nt2 = 0; nt2 < 8; ++nt2)
            out[(size_t)iq * 2048 + h * 128 + nt2 * 16 + cc] = f * oacc[nt2][j];
    }
}

// ---------------------------------------------------------------------------
// Single-branch sparse attention (IS_SEL: selected-blocks branch; else
// 512-window branch).  64-query tile, 4 waves, reg-staged KV prefetch,
// exp2-domain online softmax.  Accumulates g * O/l into out.
// ---------------------------------------------------------------------------
template <bool IS_SEL>
__global__ __launch_bounds__(256) void attn_main(
    const unsigned short* __restrict__ qbf,   // [h][s][128] bf16
    const unsigned short* __restrict__ kbf,   // [h][s][128] bf16
    const unsigned short* __restrict__ vtbf,  // [h][128][2048] bf16 (V^T)
    const float* __restrict__ gates,          // [h][s][3]
    const unsigned long long* __restrict__ bmask,
    float* __restrict__ out)                  // [s][2048], accumulate
{
    const int h  = blockIdx.y;
    const int qt = IS_SEL ? 31 - (int)blockIdx.x : (int)blockIdx.x;
    const int i0 = qt * 64;
    const int tid = (int)threadIdx.x;
    const int l = tid & 63, w = tid >> 6;
    const int cc = l & 15,  g = l >> 4;

    __shared__ short Ks[64][136];     // K chunk [tok][d], +8 pad
    __shared__ short Vt[128][72];     // V^T chunk [d][tok], +8 pad
    __shared__ short Ps[4][16][72];   // P [wave][row][tok], +8 pad

    unsigned long long um = 0;
    if (IS_SEL){
        um = bmask[(size_t)h * 2048 + i0 + l];
        #pragma unroll
        for (int off = 1; off < 64; off <<= 1) um |= __shfl_xor(um, off);
    }

    unsigned long long bm[4];
    int mrow[4];
    #pragma unroll
    for (int j = 0; j < 4; ++j){
        mrow[j] = i0 + w * 16 + g * 4 + j;
        bm[j] = IS_SEL ? bmask[(size_t)h * 2048 + mrow[j]] : 0ULL;
    }

    bf16x8 qfrag[4];
    {
        const unsigned short* qrow = &qbf[((size_t)h * 2048 + i0 + w * 16 + cc) * 128];
        #pragma unroll
        for (int kk = 0; kk < 4; ++kk)
            qfrag[kk] = *(const bf16x8*)&qrow[kk * 32 + g * 8];
    }

    f32x4 oacc[8] = {};
    float mrun[4], lrun[4];
    #pragma unroll
    for (int j = 0; j < 4; ++j){ mrun[j] = -1e30f; lrun[j] = 0.f; }

    const int chlo = IS_SEL ? 0 : (qt > 8 ? qt - 8 : 0);
    auto needed = [&](int ch)->bool {
        return IS_SEL ? (((um >> (2 * ch)) & 3ULL) != 0ULL) : true;
    };

    bf16x8 rk[4], rv[4];
    auto LOADC = [&](int ch){
        #pragma unroll
        for (int it = 0; it < 4; ++it){
            int c = tid + it * 256;
            rk[it] = *(const bf16x8*)&kbf[((size_t)h * 2048 + ch * 64 + (c >> 4)) * 128 + (c & 15) * 8];
            rv[it] = *(const bf16x8*)&vtbf[((size_t)h * 128 + (c >> 3)) * 2048 + ch * 64 + (c & 7) * 8];
        }
    };
    auto STOREC = [&](){
        #pragma unroll
        for (int it = 0; it < 4; ++it){
            int c = tid + it * 256;
            *(bf16x8*)&Ks[c >> 4][(c & 15) * 8] = rk[it];
            *(bf16x8*)&Vt[c >> 3][(c & 7) * 8] = rv[it];
        }
    };

    int cur = chlo;
    while (cur <= qt && !needed(cur)) ++cur;   // chunk qt always needed
    LOADC(cur); STOREC(); __syncthreads();

    while (cur <= qt){
        int nxt = cur + 1;
        while (nxt <= qt && !needed(nxt)) ++nxt;
        const bool more = (nxt <= qt);
        if (more) LOADC(nxt);

        // ---- QK^T ----
        f32x4 sacc[4] = {};
        #pragma unroll
        for (int kk = 0; kk < 4; ++kk)
            #pragma unroll
            for (int nt = 0; nt < 4; ++nt){
                bf16x8 kfr = *(const bf16x8*)&Ks[nt * 16 + cc][kk * 32 + g * 8];
                sacc[nt] = mfma16(qfrag[kk], kfr, sacc[nt]);
            }

        // ---- masked online softmax (exp2 domain) ----
        const int tbase = cur * 64;
        #pragma unroll
        for (int j = 0; j < 4; ++j){
            const int iq = mrow[j];
            float sj[4]; bool ok[4];
            float mx = -1e30f;
            #pragma unroll
            for (int nt = 0; nt < 4; ++nt){
                int t = tbase + nt * 16 + cc;
                bool o = (t <= iq) &&
                         (IS_SEL ? (((bm[j] >> (t >> 5)) & 1ULL) != 0ULL)
                                 : ((iq - t) < 512));
                float s = sacc[nt][j] * SCL2E;
                sj[nt] = s; ok[nt] = o;
                if (o) mx = fmaxf(mx, s);
            }
            #pragma unroll
            for (int off = 1; off < 16; off <<= 1)
                mx = fmaxf(mx, __shfl_xor(mx, off));
            float mnew = fmaxf(mrun[j], mx);
            float alpha = exp2f(mrun[j] - mnew);
            float psum = 0.f;
            #pragma unroll
            for (int nt = 0; nt < 4; ++nt){
                float p = ok[nt] ? exp2f(sj[nt] - mnew) : 0.f;
                psum += p;
                Ps[w][g * 4 + j][nt * 16 + cc] = (short)f2bfu(p);
            }
            #pragma unroll
            for (int off = 1; off < 16; off <<= 1)
                psum += __shfl_xor(psum, off);
            mrun[j] = mnew;
            lrun[j] = lrun[j] * alpha + psum;
            #pragma unroll
            for (int nt2 = 0; nt2 < 8; ++nt2) oacc[nt2][j] *= alpha;
        }
        __syncthreads();

        // ---- PV ----
        #pragma unroll
        for (int kk = 0; kk < 2; ++kk){
            bf16x8 pa = *(const bf16x8*)&Ps[w][cc][kk * 32 + g * 8];
            #pragma unroll
            for (int nt2 = 0; nt2 < 8; ++nt2){
                bf16x8 vfr = *(const bf16x8*)&Vt[nt2 * 16 + cc][kk * 32 + g * 8];
                oacc[nt2] = mfma16(pa, vfr, oacc[nt2]);
            }
        }
        __syncthreads();
        if (more){ STOREC(); __syncthreads(); }
        cur = more ? nxt : qt + 1;
    }

    // ---- epilogue: out += g * O / l ----
    const int GI = IS_SEL ? 1 : 2;
    #pragma unroll
    for (int j = 0; j < 4; ++j){
        const int iq = mrow[j];
        float gv  = gates[((size_t)h * 2048 + iq) * 3 + GI];
        float inv = gv / lrun[j];
        #pragma unroll
        for (int nt2 = 0; nt2 < 8; ++nt2){
            int d = nt2 * 16 + cc;
            out[(size_t)iq * 2048 + h * 128 + d] += oacc[nt2][j] * inv;
        }
    }
}

// ---------------------------------------------------------------------------
// workspace layout (bytes); peak ~74.7 MB
// ---------------------------------------------------------------------------
#define MB ((size_t)1 << 20)
#define OFF_QF   ((size_t)0)          // 16 MB  q f32 [h][s][d]
#define OFF_KF   (16 * MB)            // 16 MB  k f32
#define OFF_VT   (32 * MB)            //  8 MB  V^T bf16 [h][d][s]
#define OFF_XH   (40 * MB)            //  8 MB  X hi bf16   (later: qbf)
#define OFF_XL   (48 * MB)            //  8 MB  X lo bf16   (later: kbf)
#define OFF_WTH  (56 * MB)            //  8 MB  W^T hi bf16
#define OFF_WTL  (64 * MB)            //  8 MB  W^T lo bf16
#define OFF_COS  (72 * MB)
#define OFF_SIN  (72 * MB + 524288)
#define OFF_KC   (72 * MB + 1048576)
#define OFF_VC   (72 * MB + 1572864)
#define OFF_GATE (72 * MB + 2097152)
#define OFF_BM   (72 * MB + 2490368)

extern "C" void kernel_launch(void* const* d_in, const int* in_sizes, int n_in,
                              void* d_out, int out_size, void* d_ws, size_t ws_size,
                              hipStream_t stream)
{
    const float* X  = (const float*)d_in[0];
    const float* Wq = (const float*)d_in[1];
    const float* bq = (const float*)d_in[2];
    const float* Wk = (const float*)d_in[3];
    const float* bk = (const float*)d_in[4];
    const float* Wv = (const float*)d_in[5];
    const float* bv = (const float*)d_in[6];
    const float* Wg = (const float*)d_in[7];
    const float* bg = (const float*)d_in[8];
    float* out = (float*)d_out;

    char* ws = (char*)d_ws;
    float* qf   = (float*)(ws + OFF_QF);
    float* kf   = (float*)(ws + OFF_KF);
    unsigned short* vtbf = (unsigned short*)(ws + OFF_VT);
    unsigned short* Xh   = (unsigned short*)(ws + OFF_XH);
    unsigned short* Xl   = (unsigned short*)(ws + OFF_XL);
    unsigned short* WTh  = (unsigned short*)(ws + OFF_WTH);
    unsigned short* WTl  = (unsigned short*)(ws + OFF_WTL);
    unsigned short* qbf  = (unsigned short*)(ws + OFF_XH);   // alias (X dead)
    unsigned short* kbf  = (unsigned short*)(ws + OFF_XL);   // alias
    float* cost  = (float*)(ws + OFF_COS);
    float* sint  = (float*)(ws + OFF_SIN);
    float* kcmp  = (float*)(ws + OFF_KC);
    float* vcmp  = (float*)(ws + OFF_VC);
    float* gatesb = (float*)(ws + OFF_GATE);
    unsigned long long* bmaskb = (unsigned long long*)(ws + OFF_BM);

    rope_table_k<<<2048, 64, 0, stream>>>(cost, sint);
    prep_split<true><<<4096, 256, 0, stream>>>(X, Xh, Xl);

    prep_wT<<<dim3(32, 32), 256, 0, stream>>>(Wq, WTh, WTl);
    gemm_bf<2><<<dim3(16, 16), 256, 0, stream>>>(Xh, Xl, WTh, WTl, bq, qf, nullptr);
    prep_wT<<<dim3(32, 32), 256, 0, stream>>>(Wk, WTh, WTl);
    gemm_bf<2><<<dim3(16, 16), 256, 0, stream>>>(Xh, Xl, WTh, WTl, bk, kf, nullptr);
    prep_wT<<<dim3(32, 32), 256, 0, stream>>>(Wv, WTh, nullptr);
    gemm_bf<1><<<dim3(16, 16), 256, 0, stream>>>(Xh, nullptr, WTh, nullptr, bv, nullptr, vtbf);

    rope_apply<<<16384, 256, 0, stream>>>(qf, kf, cost, sint);
    prep_split<false><<<4096, 256, 0, stream>>>(qf, qbf, nullptr);
    prep_split<false><<<4096, 256, 0, stream>>>(kf, kbf, nullptr);

    cmp_mean<<<512, 256, 0, stream>>>(kf, vtbf, kcmp, vcmp);
    gates_k<<<512, 256, 0, stream>>>(qf, Wg, bg, gatesb);
    cmp_attn<<<dim3(32, 16), 256, 0, stream>>>(qf, kcmp, vcmp, gatesb, out, bmaskb);

    attn_main<false><<<dim3(32, 16), 256, 0, stream>>>(qbf, kbf, vtbf, gatesb, bmaskb, out);
    attn_main<true><<<dim3(32, 16), 256, 0, stream>>>(qbf, kbf, vtbf, gatesb, bmaskb, out);
}